// Round 2
// baseline (532.057 us; speedup 1.0000x reference)
//
#include <hip/hip_runtime.h>
#include <hip/hip_bf16.h>
#include <stdint.h>

// EfficientAttention: B=16, C=512, HW=4096, HEADS=8, hk=hv=64
// N = B*HW = 65536.

typedef __attribute__((ext_vector_type(8))) short bf16x8;
typedef __attribute__((ext_vector_type(8))) unsigned short u16x8;
typedef __attribute__((ext_vector_type(4))) unsigned short u16x4;
typedef __attribute__((ext_vector_type(4))) float f32x4;

__device__ __forceinline__ float bf2f(unsigned short u) {
  union { unsigned int i; float f; } v; v.i = ((unsigned int)u) << 16; return v.f;
}
__device__ __forceinline__ unsigned short f2bf(float f) {
  union { float f; unsigned int i; } v; v.f = f;
  unsigned int u = v.i;
  return (unsigned short)((u + 0x7FFFu + ((u >> 16) & 1u)) >> 16);
}
__device__ __forceinline__ void gl_lds16(const void* g, void* l) {
  __builtin_amdgcn_global_load_lds((const __attribute__((address_space(1))) void*)g,
                                   (__attribute__((address_space(3))) void*)l, 16, 0, 0);
}

// ---------------- K0: pack Wk|Wq|Wv (stacked) to bf16 -----------------------
__global__ void k0_pack_w(const float* __restrict__ Wk, const float* __restrict__ Wq,
                          const float* __restrict__ Wv, unsigned short* __restrict__ Wkqv) {
  int idx = blockIdx.x * 256 + threadIdx.x;   // < 1536*512
  int o = idx >> 9, c = idx & 511;
  float v;
  if (o < 512) v = Wk[o * 512 + c];
  else if (o < 1024) v = Wq[(o - 512) * 512 + c];
  else v = Wv[(o - 1024) * 512 + c];
  Wkqv[idx] = f2bf(v);
}

// ---------------- K1: x[b][c][l] fp32 -> XbT[b*4096+l][c] bf16 (transpose) --
__global__ void k1_transpose_x(const float* __restrict__ x, unsigned short* __restrict__ XbT) {
  __shared__ unsigned short ts[64][68];
  int l0 = blockIdx.x * 64, c0 = blockIdx.y * 64, b = blockIdx.z;
  int t = threadIdx.x;
  const float* xb = x + (size_t)b * (512 * 4096);
#pragma unroll
  for (int i = 0; i < 4; i++) {
    int f = i * 256 + t;
    int cl = f >> 4, l4 = (f & 15) * 4;
    const float4 v = *(const float4*)(xb + (size_t)(c0 + cl) * 4096 + l0 + l4);
    ts[cl][l4]     = f2bf(v.x);
    ts[cl][l4 + 1] = f2bf(v.y);
    ts[cl][l4 + 2] = f2bf(v.z);
    ts[cl][l4 + 3] = f2bf(v.w);
  }
  __syncthreads();
#pragma unroll
  for (int i = 0; i < 4; i++) {
    int wv = i * 256 + t;
    int ll = wv >> 4, c4 = (wv & 15) * 4;
    u16x4 o;
    o.x = ts[c4][ll]; o.y = ts[c4 + 1][ll]; o.z = ts[c4 + 2][ll]; o.w = ts[c4 + 3][ll];
    *(u16x4*)(XbT + (size_t)(b * 4096 + l0 + ll) * 512 + c0 + c4) = o;
  }
}

// ---------------- gemm256: persistent 256x256 tiles, BK=64, 8-phase ---------
// Each block owns ONE n-column (256 spatial cols) and TWO m-tiles; the staging
// pipeline (counted vmcnt(4)) runs continuously across the 16 K-tiles; the
// first m-tile's epilogue executes between kk=7 and kk=8 with tile-1 staging
// loads already in flight -> prologue/drain paid once, epilogue overlapped.
// EPI=0: 768 blocks = 256 cols x 3 m-pairs ({0,1}=K,{2,3}=Q,{4,5}=V). The 3
//        blocks of one column co-locate on one XCD (co-dispatched) so the
//        B-column stream is fetched once into that XCD's L2.
// EPI=1: 256 blocks = 256 cols x 1 (m-tiles {0,1}).
#define PHASE(bb_, q_, STAGE_STMT, TAIL_STMT)                                   \
  {                                                                             \
    const int ar_ = wm * 128 + (q_) * 32 + col;                                 \
    bf16x8 a00 = LDF((bb_), ar_, quad);                                         \
    bf16x8 a01 = LDF((bb_), ar_, 4 + quad);                                     \
    bf16x8 a10 = LDF((bb_), ar_ + 16, quad);                                    \
    bf16x8 a11 = LDF((bb_), ar_ + 16, 4 + quad);                                \
    if ((q_) == 0) {                                                            \
      _Pragma("unroll") for (int nf = 0; nf < 4; ++nf) {                        \
        bfr[nf][0] = LDF((bb_) + 16384, wn * 64 + nf * 16 + col, quad);         \
        bfr[nf][1] = LDF((bb_) + 16384, wn * 64 + nf * 16 + col, 4 + quad);     \
      }                                                                         \
    }                                                                           \
    STAGE_STMT;                                                                 \
    __builtin_amdgcn_s_barrier();                                               \
    __builtin_amdgcn_s_setprio(1);                                              \
    _Pragma("unroll") for (int nf = 0; nf < 4; ++nf) {                          \
      acc[(q_)*2][nf]   = __builtin_amdgcn_mfma_f32_16x16x32_bf16(a00, bfr[nf][0], acc[(q_)*2][nf], 0, 0, 0);   \
      acc[(q_)*2+1][nf] = __builtin_amdgcn_mfma_f32_16x16x32_bf16(a10, bfr[nf][0], acc[(q_)*2+1][nf], 0, 0, 0); \
      acc[(q_)*2][nf]   = __builtin_amdgcn_mfma_f32_16x16x32_bf16(a01, bfr[nf][1], acc[(q_)*2][nf], 0, 0, 0);   \
      acc[(q_)*2+1][nf] = __builtin_amdgcn_mfma_f32_16x16x32_bf16(a11, bfr[nf][1], acc[(q_)*2+1][nf], 0, 0, 0); \
    }                                                                           \
    __builtin_amdgcn_s_setprio(0);                                              \
    asm volatile("s_waitcnt lgkmcnt(0)" ::: "memory");                          \
    TAIL_STMT;                                                                  \
    __builtin_amdgcn_s_barrier();                                               \
  }

template <int EPI>
__global__ void __launch_bounds__(512, 2) gemm256(
    const unsigned short* __restrict__ Aall, const unsigned short* __restrict__ Ball,
    const float* __restrict__ bias0, const float* __restrict__ bias1,
    const float* __restrict__ bias2, unsigned short* __restrict__ outU,
    float* __restrict__ outF) {
  __shared__ unsigned short smem[65536];  // 128 KiB
  const int t = threadIdx.x;
  const int lane = t & 63, w = t >> 6;
  const int wm = w >> 2, wn = w & 3;
  const int col = lane & 15, quad = lane >> 4;
  const int r8 = lane >> 3, sg = lane & 7;
  const int swz = sg ^ r8;  // pre-swizzled global seg for linear LDS dest

  const int g = blockIdx.x;
  const int xcd = g & 7, jidx = g >> 3;
  int ncol, mt0, mt1;
  if (EPI == 0) {
    const int cl = jidx / 3, mp = jidx - cl * 3;   // 96 = 32 cols x 3 m-pairs
    ncol = xcd * 32 + cl; mt0 = mp * 2; mt1 = mp * 2 + 1;
  } else {
    ncol = xcd * 32 + jidx;                        // 32 cols per XCD
    mt0 = 0; mt1 = 1;
  }
  const int n0 = ncol * 256;

  const unsigned short* Abase = (EPI == 0)
      ? Aall : Aall + (size_t)(n0 >> 12) * 262144;
  const unsigned short* A0 = Abase + (size_t)mt0 * 256 * 512;
  const unsigned short* A1 = Abase + (size_t)mt1 * 256 * 512;
  const unsigned short* B = Ball + (size_t)n0 * 512;

  // stage one 128-row half-tile (16 KB): 2 x global_load_lds(16B) per thread
  auto STG = [&](const unsigned short* gbase, int ldsOff) {
    gl_lds16(gbase + (size_t)(w * 8 + r8) * 512 + swz * 8,
             (char*)smem + ((size_t)ldsOff + (size_t)(w * 8) * 64) * 2);
    gl_lds16(gbase + (size_t)(64 + w * 8 + r8) * 512 + swz * 8,
             (char*)smem + ((size_t)ldsOff + (size_t)(64 + w * 8) * 64) * 2);
  };
  // swizzled fragment read (ushort offsets; row stride 64 ushorts)
  auto LDF = [&](int baseOff, int row, int cb) -> bf16x8 {
    int ch = cb ^ (row & 7);
    return *(const bf16x8*)(smem + baseOff + row * 64 + ch * 8);
  };

  f32x4 acc[8][4];
  bf16x8 bfr[4][2];
#pragma unroll
  for (int i = 0; i < 8; ++i)
#pragma unroll
    for (int jj = 0; jj < 4; ++jj) acc[i][jj] = (f32x4){0.f, 0.f, 0.f, 0.f};

  // epilogue for one finished 256-row m-tile (registers/global only; no LDS,
  // no barriers -> safe to run inside the pipeline between kk=7 and kk=8)
  auto epilogue = [&](int m0) {
    if (EPI == 1) {
      const int bIdx = n0 >> 12;
      const int l0 = (n0 & 4095) + wn * 64 + col;
      float* obp = outF + (size_t)bIdx * 2097152;
#pragma unroll
      for (int mf = 0; mf < 8; ++mf) {
        const int row0 = m0 + wm * 128 + mf * 16 + quad * 4;
#pragma unroll
        for (int r = 0; r < 4; ++r) {
          const float bi = bias0[row0 + r];
          float* op = obp + (size_t)(row0 + r) * 4096 + l0;
#pragma unroll
          for (int nf = 0; nf < 4; ++nf) op[nf * 16] = acc[mf][nf][r] + bi;
        }
      }
      return;
    }
    if (m0 < 512 || m0 >= 1024) {
      const float* bb_ = (m0 < 512) ? bias0 : bias2;
      const int boff = (m0 < 512) ? 0 : 1024;
#pragma unroll
      for (int mf = 0; mf < 8; ++mf) {
        const int row0 = m0 + wm * 128 + mf * 16 + quad * 4;
#pragma unroll
        for (int r = 0; r < 4; ++r) {
          const float bi = bb_[row0 + r - boff];
          unsigned short* op = outU + (size_t)(row0 + r) * 65536 + n0 + wn * 64 + col;
#pragma unroll
          for (int nf = 0; nf < 4; ++nf) op[nf * 16] = f2bf(acc[mf][nf][r] + bi);
        }
      }
    } else {
      // Q rows: in-wave softmax over the head's 64 channels per spatial column
      unsigned short* QT = outU + (size_t)512 * 65536;
      const int cq0 = (m0 - 512) + wm * 128;
#pragma unroll
      for (int mf = 0; mf < 8; ++mf) {
        const int row0 = cq0 + mf * 16 + quad * 4;
#pragma unroll
        for (int r = 0; r < 4; ++r) {
          const float bi = bias1[row0 + r];
#pragma unroll
          for (int nf = 0; nf < 4; ++nf) acc[mf][nf][r] += bi;
        }
      }
#pragma unroll
      for (int h2 = 0; h2 < 2; ++h2)
#pragma unroll
        for (int nf = 0; nf < 4; ++nf) {
          float mx = -1e30f;
#pragma unroll
          for (int mf2 = 0; mf2 < 4; ++mf2)
#pragma unroll
            for (int r = 0; r < 4; ++r) mx = fmaxf(mx, acc[h2 * 4 + mf2][nf][r]);
          mx = fmaxf(mx, __shfl_xor(mx, 16));
          mx = fmaxf(mx, __shfl_xor(mx, 32));
          float s = 0.f;
#pragma unroll
          for (int mf2 = 0; mf2 < 4; ++mf2)
#pragma unroll
            for (int r = 0; r < 4; ++r) s += __expf(acc[h2 * 4 + mf2][nf][r] - mx);
          s += __shfl_xor(s, 16);
          s += __shfl_xor(s, 32);
          const float inv = 1.0f / s;
          const int n = n0 + wn * 64 + nf * 16 + col;
#pragma unroll
          for (int mf2 = 0; mf2 < 4; ++mf2) {
            u16x4 o;
#pragma unroll
            for (int r = 0; r < 4; ++r)
              o[r] = f2bf(__expf(acc[h2 * 4 + mf2][nf][r] - mx) * inv);
            *(u16x4*)(QT + (size_t)n * 512 + cq0 + h2 * 64 + mf2 * 16 + quad * 4) = o;
          }
        }
    }
  };

  // prologue: B(0)h0,h1; A(0)h0,h1; B(1)h0,h1  (12 loads in flight)
  STG(B, 16384);
  STG(B + (size_t)128 * 512, 16384 + 8192);
  STG(A0, 0);
  STG(A0 + (size_t)128 * 512, 8192);
  STG(B + 64, 32768 + 16384);
  STG(B + (size_t)128 * 512 + 64, 32768 + 16384 + 8192);
  asm volatile("s_waitcnt vmcnt(4)" ::: "memory");  // B(0),A(0) landed
  __builtin_amdgcn_s_barrier();

  // continuous 16-K-tile pipeline over both m-tiles (kk = global K index)
#pragma unroll 2
  for (int kk = 0; kk < 16; ++kk) {
    const int bb = (kk & 1) * 32768;
    const int ob = bb ^ 32768;
    const unsigned short* An = (((kk + 1) & 8) ? A1 : A0) + ((kk + 1) & 7) * 64;
    const unsigned short* Bn = B + ((kk + 2) & 7) * 64;
    const bool sA = (kk + 1) < 16;
    const bool sB = (kk + 2) < 16;
    PHASE(bb, 0, { if (sA) STG(An, ob); }, (void)0);
    PHASE(bb, 1, { if (sA) STG(An + (size_t)128 * 512, ob + 8192); }, (void)0);
    PHASE(bb, 2, { if (sB) STG(Bn, bb + 16384); }, (void)0);
    PHASE(bb, 3, { if (sB) STG(Bn + (size_t)128 * 512, bb + 16384 + 8192); },
          {
            if (kk < 14)       { asm volatile("s_waitcnt vmcnt(4)" ::: "memory"); }
            else if (kk == 14) { asm volatile("s_waitcnt vmcnt(0)" ::: "memory"); }
          });
    if (kk == 7) {
      epilogue(mt0 * 256);
#pragma unroll
      for (int i = 0; i < 8; ++i)
#pragma unroll
        for (int jj = 0; jj < 4; ++jj) acc[i][jj] = (f32x4){0.f, 0.f, 0.f, 0.f};
    }
  }
  epilogue(mt1 * 256);
}

// ---------------- K5: online-flash ctx partials per l-split -----------------
__global__ void __launch_bounds__(256) k5_ctx(const unsigned short* __restrict__ KQV,
                                              float* __restrict__ ctxp,
                                              float2* __restrict__ Msp) {
  __shared__ unsigned short Ks[64 * 32];
  __shared__ unsigned short Vs[64 * 32];
  __shared__ float red[64 * 4];
  int t = threadIdx.x;
  int lane = t & 63, w = t >> 6;
  int col = lane & 15, quad = lane >> 4;
  int s = blockIdx.x & 7;
  int h = (blockIdx.x >> 3) & 7;
  int b = blockIdx.x >> 6;
  int row = t >> 2, seg = t & 3;
  const unsigned short* Kbase = KQV + (size_t)(h * 64) * 65536 + b * 4096 + s * 512;
  const unsigned short* Vbase = KQV + (size_t)(1024 + h * 64) * 65536 + b * 4096 + s * 512;
  const unsigned short* krow = Kbase + (size_t)row * 65536;

  float mx = -1e30f;
#pragma unroll
  for (int kt = 0; kt < 16; kt++) {
    u16x8 kv = *(const u16x8*)(krow + kt * 32 + seg * 8);
#pragma unroll
    for (int jj = 0; jj < 8; jj++) mx = fmaxf(mx, bf2f(kv[jj]));
  }
  red[row * 4 + seg] = mx;
  __syncthreads();
  float m_row = fmaxf(fmaxf(red[row * 4], red[row * 4 + 1]),
                      fmaxf(red[row * 4 + 2], red[row * 4 + 3]));

  float sexp = 0.f;
  f32x4 zero = {0.f, 0.f, 0.f, 0.f};
  f32x4 acc[4];
#pragma unroll
  for (int i = 0; i < 4; i++) acc[i] = zero;
  for (int kt = 0; kt < 16; kt++) {
    int l0 = kt * 32;
    u16x8 kv = *(const u16x8*)(krow + l0 + seg * 8);
    u16x8 ke;
#pragma unroll
    for (int jj = 0; jj < 8; jj++) {
      float e = __expf(bf2f(kv[jj]) - m_row);
      sexp += e;
      ke[jj] = f2bf(e);
    }
    __syncthreads();
    *(u16x8*)(Ks + t * 8) = ke;
    gl_lds16(Vbase + (size_t)row * 65536 + l0 + seg * 8, (char*)Vs + (t & ~63) * 16);
    __syncthreads();
    bf16x8 a = *(const bf16x8*)(Ks + (w * 16 + col) * 32 + quad * 8);
#pragma unroll
    for (int nt = 0; nt < 4; nt++) {
      bf16x8 vb = *(const bf16x8*)(Vs + (nt * 16 + col) * 32 + quad * 8);
      acc[nt] = __builtin_amdgcn_mfma_f32_16x16x32_bf16(a, vb, acc[nt], 0, 0, 0);
    }
  }
  red[row * 4 + seg] = sexp;
  float* cb = ctxp + (((size_t)s * 16 + b) * 8 + h) * 4096;
#pragma unroll
  for (int nt = 0; nt < 4; nt++)
#pragma unroll
    for (int r = 0; r < 4; r++)
      cb[(w * 16 + quad * 4 + r) * 64 + nt * 16 + col] = acc[nt][r];
  __syncthreads();
  if (seg == 0) {
    float s_row = red[row * 4] + red[row * 4 + 1] + red[row * 4 + 2] + red[row * 4 + 3];
    Msp[((size_t)(b * 8 + h) * 64 + row) * 8 + s] = make_float2(m_row, s_row);
  }
}

// ---------------- K6: fused rescale-combine + Wr fold -> Mb (bf16) ----------
__global__ void __launch_bounds__(256) k6_fold(const float* __restrict__ Wr,
                                               const float* __restrict__ ctxp,
                                               const float2* __restrict__ Msp,
                                               unsigned short* __restrict__ Mb) {
  __shared__ float gf[8][64];
  __shared__ float ctxs[64][64];
  int oc = blockIdx.x, h = blockIdx.y, b = blockIdx.z;
  int t = threadIdx.x;
  if (t < 64) {
    int kc = t;
    const float2* mp = Msp + ((size_t)(b * 8 + h) * 64 + kc) * 8;
    float2 v[8];
    float m = -1e30f;
#pragma unroll
    for (int s = 0; s < 8; s++) { v[s] = mp[s]; m = fmaxf(m, v[s].x); }
    float f[8], ssum = 0.f;
#pragma unroll
    for (int s = 0; s < 8; s++) { f[s] = __expf(v[s].x - m); ssum += v[s].y * f[s]; }
    float inv = 1.0f / ssum;
#pragma unroll
    for (int s = 0; s < 8; s++) gf[s][kc] = f[s] * inv;
  }
  __syncthreads();
#pragma unroll
  for (int i = 0; i < 16; i++) {
    int p = i * 256 + t;
    int kc = p >> 6;
    float a = 0.f;
#pragma unroll
    for (int s = 0; s < 8; s++)
      a += ctxp[(((size_t)s * 16 + b) * 8 + h) * 4096 + p] * gf[s][kc];
    ((float*)ctxs)[p] = a;
  }
  __syncthreads();
  int o = oc * 128 + (t >> 1);
  int kh = (t & 1) * 32;
  const float* wrp = Wr + (size_t)o * 512 + h * 64;
  float acc2[32];
#pragma unroll
  for (int kc = 0; kc < 32; kc++) acc2[kc] = 0.f;
#pragma unroll
  for (int v4 = 0; v4 < 16; v4++) {
    float4 wv = *(const float4*)(wrp + v4 * 4);
#pragma unroll
    for (int kc = 0; kc < 32; kc++) {
      const float4 c4 = *(const float4*)(&ctxs[kh + kc][v4 * 4]);
      acc2[kc] += wv.x * c4.x + wv.y * c4.y + wv.z * c4.z + wv.w * c4.w;
    }
  }
  unsigned short* mp = Mb + (size_t)b * 262144 + (size_t)o * 512 + h * 64 + kh;
#pragma unroll
  for (int jj = 0; jj < 4; jj++) {
    u16x8 ov;
#pragma unroll
    for (int e = 0; e < 8; e++) ov[e] = f2bf(acc2[jj * 8 + e]);
    *(u16x8*)(mp + jj * 8) = ov;
  }
}

extern "C" void kernel_launch(void* const* d_in, const int* in_sizes, int n_in,
                              void* d_out, int out_size, void* d_ws, size_t ws_size,
                              hipStream_t stream) {
  const float* x  = (const float*)d_in[0];
  const float* Wk = (const float*)d_in[1];
  const float* bk = (const float*)d_in[2];
  const float* Wq = (const float*)d_in[3];
  const float* bq = (const float*)d_in[4];
  const float* Wv = (const float*)d_in[5];
  const float* bv = (const float*)d_in[6];
  const float* Wr = (const float*)d_in[7];
  const float* br = (const float*)d_in[8];
  float* out = (float*)d_out;

  char* ws = (char*)d_ws;
  const size_t MiB = 1024 * 1024;
  unsigned short* XbT  = (unsigned short*)ws;
  unsigned short* Wkqv = (unsigned short*)(ws + 64 * MiB);
  unsigned short* KQV  = (unsigned short*)(ws + 64 * MiB + 1536 * 1024);
  unsigned short* QT   = KQV + (size_t)512 * 65536;
  float2*         Msp  = (float2*)ws;
  float*          ctxp = (float*)(ws + 1 * MiB);
  unsigned short* Mb   = (unsigned short*)(ws + 20 * MiB);

  k0_pack_w<<<3072, 256, 0, stream>>>(Wk, Wq, Wv, Wkqv);
  k1_transpose_x<<<dim3(64, 8, 16), 256, 0, stream>>>(x, XbT);
  gemm256<0><<<768, 512, 0, stream>>>(Wkqv, XbT, bk, bq, bv, KQV, nullptr);
  k5_ctx<<<1024, 256, 0, stream>>>(KQV, ctxp, Msp);
  k6_fold<<<dim3(4, 8, 16), 256, 0, stream>>>(Wr, ctxp, Msp, Mb);
  gemm256<1><<<256, 512, 0, stream>>>(Mb, QT, br, nullptr, nullptr, nullptr, out);
}

// Round 3
// 493.865 us; speedup vs baseline: 1.0773x; 1.0773x over previous
//
#include <hip/hip_runtime.h>
#include <hip/hip_bf16.h>
#include <stdint.h>

// EfficientAttention: B=16, C=512, HW=4096, HEADS=8, hk=hv=64
// N = B*HW = 65536.

typedef __attribute__((ext_vector_type(8))) short bf16x8;
typedef __attribute__((ext_vector_type(8))) unsigned short u16x8;
typedef __attribute__((ext_vector_type(4))) unsigned short u16x4;
typedef __attribute__((ext_vector_type(4))) float f32x4;

__device__ __forceinline__ float bf2f(unsigned short u) {
  union { unsigned int i; float f; } v; v.i = ((unsigned int)u) << 16; return v.f;
}
__device__ __forceinline__ unsigned short f2bf(float f) {
  union { float f; unsigned int i; } v; v.f = f;
  unsigned int u = v.i;
  return (unsigned short)((u + 0x7FFFu + ((u >> 16) & 1u)) >> 16);
}
__device__ __forceinline__ void gl_lds16(const void* g, void* l) {
  __builtin_amdgcn_global_load_lds((const __attribute__((address_space(1))) void*)g,
                                   (__attribute__((address_space(3))) void*)l, 16, 0, 0);
}

// ---------------- K0: pack Wk|Wq|Wv (stacked) to bf16 -----------------------
__global__ void k0_pack_w(const float* __restrict__ Wk, const float* __restrict__ Wq,
                          const float* __restrict__ Wv, unsigned short* __restrict__ Wkqv) {
  int idx = blockIdx.x * 256 + threadIdx.x;   // < 1536*512
  int o = idx >> 9, c = idx & 511;
  float v;
  if (o < 512) v = Wk[o * 512 + c];
  else if (o < 1024) v = Wq[(o - 512) * 512 + c];
  else v = Wv[(o - 1024) * 512 + c];
  Wkqv[idx] = f2bf(v);
}

// ---------------- K1: x[b][c][l] fp32 -> XbT[b*4096+l][c] bf16 (transpose) --
__global__ void k1_transpose_x(const float* __restrict__ x, unsigned short* __restrict__ XbT) {
  __shared__ unsigned short ts[64][68];
  int l0 = blockIdx.x * 64, c0 = blockIdx.y * 64, b = blockIdx.z;
  int t = threadIdx.x;
  const float* xb = x + (size_t)b * (512 * 4096);
#pragma unroll
  for (int i = 0; i < 4; i++) {
    int f = i * 256 + t;
    int cl = f >> 4, l4 = (f & 15) * 4;
    const float4 v = *(const float4*)(xb + (size_t)(c0 + cl) * 4096 + l0 + l4);
    ts[cl][l4]     = f2bf(v.x);
    ts[cl][l4 + 1] = f2bf(v.y);
    ts[cl][l4 + 2] = f2bf(v.z);
    ts[cl][l4 + 3] = f2bf(v.w);
  }
  __syncthreads();
#pragma unroll
  for (int i = 0; i < 4; i++) {
    int wv = i * 256 + t;
    int ll = wv >> 4, c4 = (wv & 15) * 4;
    u16x4 o;
    o.x = ts[c4][ll]; o.y = ts[c4 + 1][ll]; o.z = ts[c4 + 2][ll]; o.w = ts[c4 + 3][ll];
    *(u16x4*)(XbT + (size_t)(b * 4096 + l0 + ll) * 512 + c0 + c4) = o;
  }
}

// ---------------- gemm128: 128x256 tile, BK=32, 2 blocks/CU -----------------
// 8 waves (2M x 4N), per-wave 64x64 output (acc = 64 VGPR -> fits 128-reg
// budget at 4 waves/SIMD => 2 blocks/CU; the co-resident block hides this
// block's prologue/epilogue/drain). LDS 48 KiB: dbuf x (A 8K + B 16K).
// 64-B LDS rows (32 bf16); 16B-chunk c of row r holds global chunk c^(r&3)
// (pre-swizzled global source, linear global_load_lds dest, swizzled ds_read).
// Per K-tile: 2 phases x {ds_read frags, stage, barrier, setprio+8 MFMA,
// lgkm(0), [vmcnt(2) tail at ph1], barrier}. Staging: A(kt+1)@ph0 into the
// other A-buf, B(kt+2)@ph1 into the current B-buf (dead after ph0's reads).
// Counted vmcnt(2) in steady state; vmcnt(0) only at kt=14 drain.
#define PHASE(bb_, p_, STAGE_STMT, TAIL_STMT)                                   \
  {                                                                             \
    const int ar_ = wm * 64 + (p_) * 32 + col;                                  \
    bf16x8 a0 = ldA((bb_), ar_);                                                \
    bf16x8 a1 = ldA((bb_), ar_ + 16);                                           \
    if ((p_) == 0) {                                                            \
      _Pragma("unroll") for (int nf = 0; nf < 4; ++nf)                          \
        bfr[nf] = ldB((bb_), wn * 64 + nf * 16 + col);                          \
    }                                                                           \
    STAGE_STMT;                                                                 \
    __builtin_amdgcn_s_barrier();                                               \
    __builtin_amdgcn_s_setprio(1);                                              \
    _Pragma("unroll") for (int nf = 0; nf < 4; ++nf) {                          \
      acc[(p_)*2][nf]   = __builtin_amdgcn_mfma_f32_16x16x32_bf16(a0, bfr[nf], acc[(p_)*2][nf], 0, 0, 0);   \
      acc[(p_)*2+1][nf] = __builtin_amdgcn_mfma_f32_16x16x32_bf16(a1, bfr[nf], acc[(p_)*2+1][nf], 0, 0, 0); \
    }                                                                           \
    __builtin_amdgcn_s_setprio(0);                                              \
    asm volatile("s_waitcnt lgkmcnt(0)" ::: "memory");                          \
    TAIL_STMT;                                                                  \
    __builtin_amdgcn_s_barrier();                                               \
  }

template <int EPI>
__global__ void __launch_bounds__(512, 4) gemm128(
    const unsigned short* __restrict__ Aall, const unsigned short* __restrict__ Ball,
    const float* __restrict__ bias0, const float* __restrict__ bias1,
    const float* __restrict__ bias2, unsigned short* __restrict__ outU,
    float* __restrict__ outF) {
  __shared__ char smem2[49152];  // A0@0, A1@8K, B0@16K, B1@32K
  const int t = threadIdx.x;
  const int lane = t & 63, w = t >> 6;
  const int wm = w >> 2, wn = w & 3;            // 2M x 4N waves
  const int col = lane & 15, quad = lane >> 4;
  const int srow = t >> 2, sch0 = t & 3;        // staging row/chunk

  const int g = blockIdx.x;
  const int xcd = g & 7, j = g >> 3;
  int mi, ni;
  if (EPI == 0) { mi = j % 12; ni = (j / 12) * 8 + xcd; }   // 3072 blocks
  else          { mi = j & 3;  ni = (j >> 2) * 8 + xcd; }   // 1024 blocks
  const int m0 = mi * 128, n0 = ni * 256;

  const unsigned short* Ag = (EPI == 0)
      ? Aall + (size_t)m0 * 512
      : Aall + (size_t)(n0 >> 12) * 262144 + (size_t)m0 * 512;
  const unsigned short* Bg = Ball + (size_t)n0 * 512;

  // stage A K-tile (8 KB, 1 gl_lds16/thread) / B K-tile half (8 KB each)
  auto stgA = [&](int kt, int buf) {
    const int ch = sch0 ^ (srow & 3);
    gl_lds16(Ag + (size_t)srow * 512 + kt * 32 + ch * 8,
             smem2 + buf * 8192 + (t & ~63) * 16);
  };
  auto stgB = [&](int kt, int buf, int half) {
    const int ch = sch0 ^ (srow & 3);
    gl_lds16(Bg + (size_t)(half * 128 + srow) * 512 + kt * 32 + ch * 8,
             smem2 + 16384 + buf * 16384 + half * 8192 + (t & ~63) * 16);
  };
  // swizzled fragment reads (byte offsets; row stride 64 B)
  auto ldA = [&](int buf, int row) -> bf16x8 {
    const int ch = quad ^ (row & 3);
    return *(const bf16x8*)(smem2 + buf * 8192 + row * 64 + ch * 16);
  };
  auto ldB = [&](int buf, int row) -> bf16x8 {
    const int ch = quad ^ (row & 3);
    return *(const bf16x8*)(smem2 + 16384 + buf * 16384 + row * 64 + ch * 16);
  };

  f32x4 acc[4][4];
  bf16x8 bfr[4];
#pragma unroll
  for (int i = 0; i < 4; ++i)
#pragma unroll
    for (int jj = 0; jj < 4; ++jj) acc[i][jj] = (f32x4){0.f, 0.f, 0.f, 0.f};

  // prologue: A(0), B(0) halves, B(1) halves = 5 loads/thread
  stgA(0, 0);
  stgB(0, 0, 0); stgB(0, 0, 1);
  stgB(1, 1, 0); stgB(1, 1, 1);
  asm volatile("s_waitcnt vmcnt(2)" ::: "memory");  // A(0),B(0) landed
  __builtin_amdgcn_s_barrier();

#pragma unroll 2
  for (int kt = 0; kt < 14; ++kt) {
    const int bb = kt & 1, ob = bb ^ 1;
    PHASE(bb, 0, stgA(kt + 1, ob), (void)0);
    PHASE(bb, 1, { stgB(kt + 2, bb, 0); stgB(kt + 2, bb, 1); },
          asm volatile("s_waitcnt vmcnt(2)" ::: "memory"));
  }
  {  // kt = 14: stage A(15) only; drain all before last tile
    PHASE(0, 0, stgA(15, 1), (void)0);
    PHASE(0, 1, (void)0, asm volatile("s_waitcnt vmcnt(0)" ::: "memory"));
  }
  {  // kt = 15: no staging
    PHASE(1, 0, (void)0, (void)0);
    PHASE(1, 1, (void)0, (void)0);
  }

  if (EPI == 1) {
    const int bIdx = n0 >> 12;
    const int l0 = (n0 & 4095) + wn * 64 + col;
    float* obp = outF + (size_t)bIdx * 2097152;
#pragma unroll
    for (int mf = 0; mf < 4; ++mf) {
      const int row0 = m0 + wm * 64 + mf * 16 + quad * 4;
#pragma unroll
      for (int r = 0; r < 4; ++r) {
        const float bi = bias0[row0 + r];
        float* op = obp + (size_t)(row0 + r) * 4096 + l0;
#pragma unroll
        for (int nf = 0; nf < 4; ++nf) op[nf * 16] = acc[mf][nf][r] + bi;
      }
    }
    return;
  }
  // ---- EPI 0: KQV epilogues
  if (m0 < 512 || m0 >= 1024) {
    const float* bb_ = (m0 < 512) ? bias0 : bias2;
    const int boff = (m0 < 512) ? 0 : 1024;
#pragma unroll
    for (int mf = 0; mf < 4; ++mf) {
      const int row0 = m0 + wm * 64 + mf * 16 + quad * 4;
#pragma unroll
      for (int r = 0; r < 4; ++r) {
        const float bi = bb_[row0 + r - boff];
        unsigned short* op = outU + (size_t)(row0 + r) * 65536 + n0 + wn * 64 + col;
#pragma unroll
        for (int nf = 0; nf < 4; ++nf) op[nf * 16] = f2bf(acc[mf][nf][r] + bi);
      }
    }
  } else {
    // Q rows: each wave owns exactly one head's 64 channels per column
    unsigned short* QT = outU + (size_t)512 * 65536;
    const int cq0 = (m0 - 512) + wm * 64;
#pragma unroll
    for (int mf = 0; mf < 4; ++mf) {
      const int ch0 = cq0 + mf * 16 + quad * 4;
#pragma unroll
      for (int r = 0; r < 4; ++r) {
        const float bi = bias1[ch0 + r];
#pragma unroll
        for (int nf = 0; nf < 4; ++nf) acc[mf][nf][r] += bi;
      }
    }
#pragma unroll
    for (int nf = 0; nf < 4; ++nf) {
      float mx = -1e30f;
#pragma unroll
      for (int mf = 0; mf < 4; ++mf)
#pragma unroll
        for (int r = 0; r < 4; ++r) mx = fmaxf(mx, acc[mf][nf][r]);
      mx = fmaxf(mx, __shfl_xor(mx, 16));
      mx = fmaxf(mx, __shfl_xor(mx, 32));
      float s = 0.f;
#pragma unroll
      for (int mf = 0; mf < 4; ++mf)
#pragma unroll
        for (int r = 0; r < 4; ++r) s += __expf(acc[mf][nf][r] - mx);
      s += __shfl_xor(s, 16);
      s += __shfl_xor(s, 32);
      const float inv = 1.0f / s;
      const int n = n0 + wn * 64 + nf * 16 + col;
#pragma unroll
      for (int mf = 0; mf < 4; ++mf) {
        u16x4 o;
#pragma unroll
        for (int r = 0; r < 4; ++r)
          o[r] = f2bf(__expf(acc[mf][nf][r] - mx) * inv);
        *(u16x4*)(QT + (size_t)n * 512 + cq0 + mf * 16 + quad * 4) = o;
      }
    }
  }
}

// ---------------- K5: online-flash ctx partials per l-split -----------------
__global__ void __launch_bounds__(256) k5_ctx(const unsigned short* __restrict__ KQV,
                                              float* __restrict__ ctxp,
                                              float2* __restrict__ Msp) {
  __shared__ unsigned short Ks[64 * 32];
  __shared__ unsigned short Vs[64 * 32];
  __shared__ float red[64 * 4];
  int t = threadIdx.x;
  int lane = t & 63, w = t >> 6;
  int col = lane & 15, quad = lane >> 4;
  int s = blockIdx.x & 7;
  int h = (blockIdx.x >> 3) & 7;
  int b = blockIdx.x >> 6;
  int row = t >> 2, seg = t & 3;
  const unsigned short* Kbase = KQV + (size_t)(h * 64) * 65536 + b * 4096 + s * 512;
  const unsigned short* Vbase = KQV + (size_t)(1024 + h * 64) * 65536 + b * 4096 + s * 512;
  const unsigned short* krow = Kbase + (size_t)row * 65536;

  float mx = -1e30f;
#pragma unroll
  for (int kt = 0; kt < 16; kt++) {
    u16x8 kv = *(const u16x8*)(krow + kt * 32 + seg * 8);
#pragma unroll
    for (int jj = 0; jj < 8; jj++) mx = fmaxf(mx, bf2f(kv[jj]));
  }
  red[row * 4 + seg] = mx;
  __syncthreads();
  float m_row = fmaxf(fmaxf(red[row * 4], red[row * 4 + 1]),
                      fmaxf(red[row * 4 + 2], red[row * 4 + 3]));

  float sexp = 0.f;
  f32x4 zero = {0.f, 0.f, 0.f, 0.f};
  f32x4 acc[4];
#pragma unroll
  for (int i = 0; i < 4; i++) acc[i] = zero;
  for (int kt = 0; kt < 16; kt++) {
    int l0 = kt * 32;
    u16x8 kv = *(const u16x8*)(krow + l0 + seg * 8);
    u16x8 ke;
#pragma unroll
    for (int jj = 0; jj < 8; jj++) {
      float e = __expf(bf2f(kv[jj]) - m_row);
      sexp += e;
      ke[jj] = f2bf(e);
    }
    __syncthreads();
    *(u16x8*)(Ks + t * 8) = ke;
    gl_lds16(Vbase + (size_t)row * 65536 + l0 + seg * 8, (char*)Vs + (t & ~63) * 16);
    __syncthreads();
    bf16x8 a = *(const bf16x8*)(Ks + (w * 16 + col) * 32 + quad * 8);
#pragma unroll
    for (int nt = 0; nt < 4; nt++) {
      bf16x8 vb = *(const bf16x8*)(Vs + (nt * 16 + col) * 32 + quad * 8);
      acc[nt] = __builtin_amdgcn_mfma_f32_16x16x32_bf16(a, vb, acc[nt], 0, 0, 0);
    }
  }
  red[row * 4 + seg] = sexp;
  float* cb = ctxp + (((size_t)s * 16 + b) * 8 + h) * 4096;
#pragma unroll
  for (int nt = 0; nt < 4; nt++)
#pragma unroll
    for (int r = 0; r < 4; r++)
      cb[(w * 16 + quad * 4 + r) * 64 + nt * 16 + col] = acc[nt][r];
  __syncthreads();
  if (seg == 0) {
    float s_row = red[row * 4] + red[row * 4 + 1] + red[row * 4 + 2] + red[row * 4 + 3];
    Msp[((size_t)(b * 8 + h) * 64 + row) * 8 + s] = make_float2(m_row, s_row);
  }
}

// ---------------- K6: fused rescale-combine + Wr fold -> Mb (bf16) ----------
__global__ void __launch_bounds__(256) k6_fold(const float* __restrict__ Wr,
                                               const float* __restrict__ ctxp,
                                               const float2* __restrict__ Msp,
                                               unsigned short* __restrict__ Mb) {
  __shared__ float gf[8][64];
  __shared__ float ctxs[64][64];
  int oc = blockIdx.x, h = blockIdx.y, b = blockIdx.z;
  int t = threadIdx.x;
  if (t < 64) {
    int kc = t;
    const float2* mp = Msp + ((size_t)(b * 8 + h) * 64 + kc) * 8;
    float2 v[8];
    float m = -1e30f;
#pragma unroll
    for (int s = 0; s < 8; s++) { v[s] = mp[s]; m = fmaxf(m, v[s].x); }
    float f[8], ssum = 0.f;
#pragma unroll
    for (int s = 0; s < 8; s++) { f[s] = __expf(v[s].x - m); ssum += v[s].y * f[s]; }
    float inv = 1.0f / ssum;
#pragma unroll
    for (int s = 0; s < 8; s++) gf[s][kc] = f[s] * inv;
  }
  __syncthreads();
#pragma unroll
  for (int i = 0; i < 16; i++) {
    int p = i * 256 + t;
    int kc = p >> 6;
    float a = 0.f;
#pragma unroll
    for (int s = 0; s < 8; s++)
      a += ctxp[(((size_t)s * 16 + b) * 8 + h) * 4096 + p] * gf[s][kc];
    ((float*)ctxs)[p] = a;
  }
  __syncthreads();
  int o = oc * 128 + (t >> 1);
  int kh = (t & 1) * 32;
  const float* wrp = Wr + (size_t)o * 512 + h * 64;
  float acc2[32];
#pragma unroll
  for (int kc = 0; kc < 32; kc++) acc2[kc] = 0.f;
#pragma unroll
  for (int v4 = 0; v4 < 16; v4++) {
    float4 wv = *(const float4*)(wrp + v4 * 4);
#pragma unroll
    for (int kc = 0; kc < 32; kc++) {
      const float4 c4 = *(const float4*)(&ctxs[kh + kc][v4 * 4]);
      acc2[kc] += wv.x * c4.x + wv.y * c4.y + wv.z * c4.z + wv.w * c4.w;
    }
  }
  unsigned short* mp = Mb + (size_t)b * 262144 + (size_t)o * 512 + h * 64 + kh;
#pragma unroll
  for (int jj = 0; jj < 4; jj++) {
    u16x8 ov;
#pragma unroll
    for (int e = 0; e < 8; e++) ov[e] = f2bf(acc2[jj * 8 + e]);
    *(u16x8*)(mp + jj * 8) = ov;
  }
}

extern "C" void kernel_launch(void* const* d_in, const int* in_sizes, int n_in,
                              void* d_out, int out_size, void* d_ws, size_t ws_size,
                              hipStream_t stream) {
  const float* x  = (const float*)d_in[0];
  const float* Wk = (const float*)d_in[1];
  const float* bk = (const float*)d_in[2];
  const float* Wq = (const float*)d_in[3];
  const float* bq = (const float*)d_in[4];
  const float* Wv = (const float*)d_in[5];
  const float* bv = (const float*)d_in[6];
  const float* Wr = (const float*)d_in[7];
  const float* br = (const float*)d_in[8];
  float* out = (float*)d_out;

  char* ws = (char*)d_ws;
  const size_t MiB = 1024 * 1024;
  unsigned short* XbT  = (unsigned short*)ws;
  unsigned short* Wkqv = (unsigned short*)(ws + 64 * MiB);
  unsigned short* KQV  = (unsigned short*)(ws + 64 * MiB + 1536 * 1024);
  unsigned short* QT   = KQV + (size_t)512 * 65536;
  float2*         Msp  = (float2*)ws;
  float*          ctxp = (float*)(ws + 1 * MiB);
  unsigned short* Mb   = (unsigned short*)(ws + 20 * MiB);

  k0_pack_w<<<3072, 256, 0, stream>>>(Wk, Wq, Wv, Wkqv);
  k1_transpose_x<<<dim3(64, 8, 16), 256, 0, stream>>>(x, XbT);
  gemm128<0><<<3072, 512, 0, stream>>>(Wkqv, XbT, bk, bq, bv, KQV, nullptr);
  k5_ctx<<<1024, 256, 0, stream>>>(KQV, ctxp, Msp);
  k6_fold<<<dim3(4, 8, 16), 256, 0, stream>>>(Wr, ctxp, Msp, Mb);
  gemm128<1><<<1024, 512, 0, stream>>>(Mb, QT, br, nullptr, nullptr, nullptr, out);
}